// Round 2
// baseline (96848.273 us; speedup 1.0000x reference)
//
#include <hip/hip_runtime.h>
#include <hip/hip_bf16.h>
#include <stdint.h>

#define NCH  256
#define EMB  1024
#define HID  2048
#define SEQL 4096

// ---------------- ws layout (bytes) ----------------
static constexpr size_t EG_OFF   = 0;
static constexpr size_t EG_BYTES = (size_t)NCH * 8192 * 4;          // 8,388,608
static constexpr size_t HS_OFF   = EG_OFF + EG_BYTES;
static constexpr size_t HS_BYTES = (size_t)SEQL * HID * 4;          // 33,554,432
static constexpr size_t HB_OFF   = HS_OFF + HS_BYTES;
static constexpr size_t HB_BYTES = 2 * HID * 4;
static constexpr size_t CF_OFF   = HB_OFF + HB_BYTES;
static constexpr size_t CF_BYTES = HID * 4;
static constexpr size_t CT_OFF   = CF_OFF + CF_BYTES;
static constexpr size_t CT_BYTES = 4096;                             // tags[256] + slack
static constexpr size_t WS_NEED  = CT_OFF + CT_BYTES;

// ---------------------------------------------------------------------------
// Kernel A: Eg[c][cu*32 + gate*8 + jl] = bias_g[j] + sum_e emb[c][e]*Wg[e][j]
// ---------------------------------------------------------------------------
__global__ __launch_bounds__(256) void eg_gemm(
    const float* __restrict__ emb,
    const float* __restrict__ Wf, const float* __restrict__ bf,
    const float* __restrict__ Wi, const float* __restrict__ bi,
    const float* __restrict__ Wo, const float* __restrict__ bo,
    const float* __restrict__ Wc, const float* __restrict__ bc,
    float* __restrict__ Eg)
{
    const int nb  = blockIdx.x & 63;
    const int cb  = blockIdx.x >> 6;
    const int tid = threadIdx.x;
    const int col = tid & 127;
    const int gate = col >> 5;
    const int jj   = col & 31;
    const int j    = nb * 32 + jj;
    const int mh   = tid >> 7;

    __shared__ float embT[32][65];
    __shared__ float Wt[32][128];

    float acc[32];
#pragma unroll
    for (int m = 0; m < 32; ++m) acc[m] = 0.f;

    for (int k0 = 0; k0 < EMB; k0 += 32) {
        __syncthreads();
        for (int i = tid; i < 64 * 32; i += 256) {
            int c = i >> 5, kk = i & 31;
            embT[kk][c] = emb[(size_t)(cb * 64 + c) * EMB + k0 + kk];
        }
        for (int i = tid; i < 32 * 128; i += 256) {
            int kk = i >> 7, cl = i & 127;
            int g2 = cl >> 5;
            int jx = nb * 32 + (cl & 31);
            const float* Wp = (g2 == 0) ? Wf : (g2 == 1) ? Wi : (g2 == 2) ? Wo : Wc;
            Wt[kk][cl] = Wp[(size_t)(k0 + kk) * HID + jx];
        }
        __syncthreads();
#pragma unroll 8
        for (int kk = 0; kk < 32; ++kk) {
            float w = Wt[kk][col];
#pragma unroll
            for (int m = 0; m < 32; ++m)
                acc[m] += embT[kk][mh * 32 + m] * w;
        }
    }
    const float* bias = (gate == 0) ? bf : (gate == 1) ? bi : (gate == 2) ? bo : bc;
    float bv = bias[j];
    for (int m = 0; m < 32; ++m) {
        int c = cb * 64 + mh * 32 + m;
        Eg[(size_t)c * 8192 + (j >> 3) * 32 + gate * 8 + (j & 7)] = acc[m] + bv;
    }
}

// ---------------------------------------------------------------------------
// Kernel B: persistent sequential LSTM, flag-based dataflow sync (no barrier).
// 256 WGs (1/CU) x 512 threads. Weights: 32 NAMED float4 per thread (forced
// register residency). Per step:
//   all: matvec partials -> S1 -> wave0: reduce+gates, publish h + tag[cu]
//   all: poll own tag, acquire, stage h float4 -> S2
// ---------------------------------------------------------------------------
#define REP32(M) M(0) M(1) M(2) M(3) M(4) M(5) M(6) M(7) M(8) M(9) M(10) M(11) \
  M(12) M(13) M(14) M(15) M(16) M(17) M(18) M(19) M(20) M(21) M(22) M(23)      \
  M(24) M(25) M(26) M(27) M(28) M(29) M(30) M(31)

__global__ __launch_bounds__(512, 2) void lstm_seq(
    const int*   __restrict__ seq,
    const float* __restrict__ h0,
    const float* __restrict__ c0,
    const float* __restrict__ Wf, const float* __restrict__ Wi,
    const float* __restrict__ Wo, const float* __restrict__ Wc,
    const float* __restrict__ Eg,
    float* __restrict__ Hs,
    float* hbuf, float* cfin, unsigned* tags)
{
    const int cu   = blockIdx.x;      // 0..255
    const int tid  = threadIdx.x;     // 0..511
    const int lane = tid & 63;
    const int wave = tid >> 6;        // 0..7
    const int d    = lane & 31;       // dot index within CU (gate*8 + jl)
    const int half = lane >> 5;       // k half
    const int gate = d >> 3;
    const int jl   = d & 7;
    const int j    = cu * 8 + jl;
    const int kb   = wave * 256 + half * 128;

    const float* W = (gate == 0) ? Wf : (gate == 1) ? Wi : (gate == 2) ? Wo : Wc;

    // ---- 128 recurrent weights in NAMED registers ----
    const float* Wb = W + (size_t)(1024 + kb) * HID + j;
#define WDECL(i) float4 w##i;
    REP32(WDECL)
#undef WDECL
#define WLOAD(i) { w##i.x = Wb[(size_t)(4*i+0)*HID]; \
                   w##i.y = Wb[(size_t)(4*i+1)*HID]; \
                   w##i.z = Wb[(size_t)(4*i+2)*HID]; \
                   w##i.w = Wb[(size_t)(4*i+3)*HID]; }
    REP32(WLOAD)
#undef WLOAD

    __shared__ __align__(16) float h_lds[HID];
    __shared__ float part[32][17];
    __shared__ int   seq_lds[SEQL];   // 16 KB

    for (int i = tid; i < SEQL; i += 512) seq_lds[i] = seq[i];
    for (int i = tid; i < HID;  i += 512) h_lds[i]   = h0[i];
    float c = 0.f;
    if (wave == 0 && lane < 8) c = c0[cu * 8 + lane];
    __syncthreads();

    unsigned* myTag = &tags[tid >> 1];   // thread covers h[4t..4t+3] -> producer tid>>1

    for (int t = 0; t < SEQL; ++t) {
        // ---- Eg prefetch (independent of h, overlaps matvec) ----
        float egv = 0.f;
        if (wave == 0)
            egv = Eg[(size_t)seq_lds[t] * 8192 + cu * 32 + d];

        // ---- matvec partial: 128 MACs from registers, h broadcast via LDS ----
        float accv[4] = {0.f, 0.f, 0.f, 0.f};
        const float4* hp = (const float4*)(h_lds + kb);
#define WMAC(i) { float4 hv = hp[i]; \
                  accv[(i)&3] += w##i.x*hv.x + w##i.y*hv.y + w##i.z*hv.z + w##i.w*hv.w; }
        REP32(WMAC)
#undef WMAC
        part[d][wave * 2 + half] = (accv[0] + accv[1]) + (accv[2] + accv[3]);
        __syncthreads();                                   // S1

        // ---- wave 0: reduce, gates, publish ----
        if (wave == 0) {
            float s = 0.f;
#pragma unroll
            for (int i = 0; i < 16; ++i) s += part[d][i];
            float pre = s + egv;
            float act;
            if (d < 24) {                       // f, i, o : sigmoid
                act = 1.f / (1.f + __expf(-pre));
            } else {                            // g : tanh
                float e = __expf(2.f * pre);
                act = 1.f - 2.f / (e + 1.f);
            }
            float iv = __shfl(act, (lane & 7) + 8,  64);
            float ov = __shfl(act, (lane & 7) + 16, 64);
            float gv = __shfl(act, (lane & 7) + 24, 64);
            if (lane < 8) {
                c = act * c + iv * gv;          // act == f on lanes 0..7
                float e2 = __expf(2.f * c);
                float th = 1.f - 2.f / (e2 + 1.f);
                float hn = ov * th;
                Hs[(size_t)t * HID + cu * 8 + lane] = hn;
                hbuf[((t + 1) & 1) * HID + cu * 8 + lane] = hn;
            }
            if (lane == 0)
                __hip_atomic_store(&tags[cu], (unsigned)(t + 1),
                                   __ATOMIC_RELEASE, __HIP_MEMORY_SCOPE_AGENT);
        }

        // ---- dataflow sync: each thread waits only for ITS producer ----
        const unsigned tgt = (unsigned)(t + 1);
        while (__hip_atomic_load(myTag, __ATOMIC_RELAXED,
                                 __HIP_MEMORY_SCOPE_AGENT) < tgt)
            __builtin_amdgcn_s_sleep(1);
        (void)__hip_atomic_load(myTag, __ATOMIC_ACQUIRE,
                                __HIP_MEMORY_SCOPE_AGENT);

        // ---- stage h(t+1) ----
        const float4* hb = (const float4*)(hbuf + ((t + 1) & 1) * HID);
        ((float4*)h_lds)[tid] = hb[tid];
        __syncthreads();                                   // S2
    }

    if (wave == 0 && lane < 8) cfin[cu * 8 + lane] = c;
}

// ---------------------------------------------------------------------------
// Kernel C: preds = Hs @ Wy + by
// ---------------------------------------------------------------------------
__global__ __launch_bounds__(256) void y_gemm(
    const float* __restrict__ Hs, const float* __restrict__ Wy,
    const float* __restrict__ by, float* __restrict__ out)
{
    const int rb  = blockIdx.x * 16;
    const int tid = threadIdx.x;
    __shared__ float A[16][68];
    float acc[16];
#pragma unroll
    for (int r = 0; r < 16; ++r) acc[r] = 0.f;

    for (int k0 = 0; k0 < HID; k0 += 64) {
        __syncthreads();
        for (int i = tid; i < 16 * 64; i += 256) {
            int r = i >> 6, kk = i & 63;
            A[r][kk] = Hs[(size_t)(rb + r) * HID + k0 + kk];
        }
        __syncthreads();
#pragma unroll 8
        for (int kk = 0; kk < 64; ++kk) {
            float b = Wy[(size_t)(k0 + kk) * NCH + tid];
#pragma unroll
            for (int r = 0; r < 16; ++r) acc[r] += A[r][kk] * b;
        }
    }
    float bv = by[tid];
    for (int r = 0; r < 16; ++r)
        out[(size_t)(rb + r) * NCH + tid] = acc[r] + bv;
}

// ---------------------------------------------------------------------------
__global__ void fin_copy(const float* __restrict__ Hs,
                         const float* __restrict__ cfin,
                         float* __restrict__ out)
{
    int i = blockIdx.x * 256 + threadIdx.x;
    if (i < HID)
        out[(size_t)SEQL * NCH + i] = Hs[(size_t)(SEQL - 1) * HID + i];
    else
        out[(size_t)SEQL * NCH + i] = cfin[i - HID];
}

// ---------------------------------------------------------------------------
extern "C" void kernel_launch(void* const* d_in, const int* in_sizes, int n_in,
                              void* d_out, int out_size, void* d_ws, size_t ws_size,
                              hipStream_t stream)
{
    if (n_in < 14 || ws_size < WS_NEED) return;

    const int*   seq = (const int*)  d_in[0];
    const float* h0  = (const float*)d_in[1];
    const float* c0  = (const float*)d_in[2];
    const float* emb = (const float*)d_in[3];
    const float* Wf  = (const float*)d_in[4];
    const float* bf  = (const float*)d_in[5];
    const float* Wi  = (const float*)d_in[6];
    const float* bi  = (const float*)d_in[7];
    const float* Wo  = (const float*)d_in[8];
    const float* bo  = (const float*)d_in[9];
    const float* Wc  = (const float*)d_in[10];
    const float* bc  = (const float*)d_in[11];
    const float* Wy  = (const float*)d_in[12];
    const float* by  = (const float*)d_in[13];

    char* ws = (char*)d_ws;
    float*    Eg   = (float*)(ws + EG_OFF);
    float*    Hs   = (float*)(ws + HS_OFF);
    float*    hbuf = (float*)(ws + HB_OFF);
    float*    cfin = (float*)(ws + CF_OFF);
    unsigned* tags = (unsigned*)(ws + CT_OFF);
    float*    out  = (float*)d_out;

    hipMemsetAsync(tags, 0, CT_BYTES, stream);

    eg_gemm<<<256, 256, 0, stream>>>(emb, Wf, bf, Wi, bi, Wo, bo, Wc, bc, Eg);

    lstm_seq<<<256, 512, 0, stream>>>(seq, h0, c0, Wf, Wi, Wo, Wc, Eg,
                                      Hs, hbuf, cfin, tags);

    y_gemm<<<256, 256, 0, stream>>>(Hs, Wy, by, out);

    fin_copy<<<16, 256, 0, stream>>>(Hs, cfin, out);
}

// Round 3
// 96702.649 us; speedup vs baseline: 1.0015x; 1.0015x over previous
//
#include <hip/hip_runtime.h>
#include <hip/hip_bf16.h>
#include <stdint.h>

#define NCH  256
#define EMB  1024
#define HID  2048
#define SEQL 4096

// ---------------- ws layout (bytes) ----------------
static constexpr size_t EG_OFF   = 0;
static constexpr size_t EG_BYTES = (size_t)NCH * 8192 * 4;          // 8,388,608
static constexpr size_t HS_OFF   = EG_OFF + EG_BYTES;
static constexpr size_t HS_BYTES = (size_t)SEQL * HID * 4;          // 33,554,432
static constexpr size_t HB_OFF   = HS_OFF + HS_BYTES;
static constexpr size_t HB_BYTES = 2 * HID * 4;
static constexpr size_t CF_OFF   = HB_OFF + HB_BYTES;
static constexpr size_t CF_BYTES = HID * 4;
static constexpr size_t CT_OFF   = CF_OFF + CF_BYTES;
static constexpr size_t CT_BYTES = 4096;                             // tags[256] + slack
static constexpr size_t WS_NEED  = CT_OFF + CT_BYTES;

// ---------------------------------------------------------------------------
// Kernel A: Eg[c][cu*32 + gate*8 + jl] = bias_g[j] + sum_e emb[c][e]*Wg[e][j]
// ---------------------------------------------------------------------------
__global__ __launch_bounds__(256) void eg_gemm(
    const float* __restrict__ emb,
    const float* __restrict__ Wf, const float* __restrict__ bf,
    const float* __restrict__ Wi, const float* __restrict__ bi,
    const float* __restrict__ Wo, const float* __restrict__ bo,
    const float* __restrict__ Wc, const float* __restrict__ bc,
    float* __restrict__ Eg)
{
    const int nb  = blockIdx.x & 63;
    const int cb  = blockIdx.x >> 6;
    const int tid = threadIdx.x;
    const int col = tid & 127;
    const int gate = col >> 5;
    const int jj   = col & 31;
    const int j    = nb * 32 + jj;
    const int mh   = tid >> 7;

    __shared__ float embT[32][65];
    __shared__ float Wt[32][128];

    float acc[32];
#pragma unroll
    for (int m = 0; m < 32; ++m) acc[m] = 0.f;

    for (int k0 = 0; k0 < EMB; k0 += 32) {
        __syncthreads();
        for (int i = tid; i < 64 * 32; i += 256) {
            int c = i >> 5, kk = i & 31;
            embT[kk][c] = emb[(size_t)(cb * 64 + c) * EMB + k0 + kk];
        }
        for (int i = tid; i < 32 * 128; i += 256) {
            int kk = i >> 7, cl = i & 127;
            int g2 = cl >> 5;
            int jx = nb * 32 + (cl & 31);
            const float* Wp = (g2 == 0) ? Wf : (g2 == 1) ? Wi : (g2 == 2) ? Wo : Wc;
            Wt[kk][cl] = Wp[(size_t)(k0 + kk) * HID + jx];
        }
        __syncthreads();
#pragma unroll 8
        for (int kk = 0; kk < 32; ++kk) {
            float w = Wt[kk][col];
#pragma unroll
            for (int m = 0; m < 32; ++m)
                acc[m] += embT[kk][mh * 32 + m] * w;
        }
    }
    const float* bias = (gate == 0) ? bf : (gate == 1) ? bi : (gate == 2) ? bo : bc;
    float bv = bias[j];
    for (int m = 0; m < 32; ++m) {
        int c = cb * 64 + mh * 32 + m;
        Eg[(size_t)c * 8192 + (j >> 3) * 32 + gate * 8 + (j & 7)] = acc[m] + bv;
    }
}

// ---------------------------------------------------------------------------
// Kernel B: persistent sequential LSTM, flag-based dataflow sync (no barrier).
// 256 WGs (1/CU) x 512 threads. Weights: 32 NAMED float4 per thread (forced
// register residency). Per step:
//   all: matvec partials -> S1 -> wave0: reduce+gates, publish h + tag[cu]
//   all: poll own tag, acquire, stage h float4 -> S2
// ---------------------------------------------------------------------------
#define REP32(M) M(0) M(1) M(2) M(3) M(4) M(5) M(6) M(7) M(8) M(9) M(10) M(11) \
  M(12) M(13) M(14) M(15) M(16) M(17) M(18) M(19) M(20) M(21) M(22) M(23)      \
  M(24) M(25) M(26) M(27) M(28) M(29) M(30) M(31)

__global__ __launch_bounds__(512, 2) void lstm_seq(
    const int*   __restrict__ seq,
    const float* __restrict__ h0,
    const float* __restrict__ c0,
    const float* __restrict__ Wf, const float* __restrict__ Wi,
    const float* __restrict__ Wo, const float* __restrict__ Wc,
    const float* __restrict__ Eg,
    float* __restrict__ Hs,
    float* hbuf, float* cfin, unsigned* tags)
{
    const int cu   = blockIdx.x;      // 0..255
    const int tid  = threadIdx.x;     // 0..511
    const int lane = tid & 63;
    const int wave = tid >> 6;        // 0..7
    const int d    = lane & 31;       // dot index within CU (gate*8 + jl)
    const int half = lane >> 5;       // k half
    const int gate = d >> 3;
    const int jl   = d & 7;
    const int j    = cu * 8 + jl;
    const int kb   = wave * 256 + half * 128;

    const float* W = (gate == 0) ? Wf : (gate == 1) ? Wi : (gate == 2) ? Wo : Wc;

    // ---- 128 recurrent weights in NAMED registers ----
    const float* Wb = W + (size_t)(1024 + kb) * HID + j;
#define WDECL(i) float4 w##i;
    REP32(WDECL)
#undef WDECL
#define WLOAD(i) { w##i.x = Wb[(size_t)(4*i+0)*HID]; \
                   w##i.y = Wb[(size_t)(4*i+1)*HID]; \
                   w##i.z = Wb[(size_t)(4*i+2)*HID]; \
                   w##i.w = Wb[(size_t)(4*i+3)*HID]; }
    REP32(WLOAD)
#undef WLOAD

    __shared__ __align__(16) float h_lds[HID];
    __shared__ float part[32][17];
    __shared__ int   seq_lds[SEQL];   // 16 KB

    for (int i = tid; i < SEQL; i += 512) seq_lds[i] = seq[i];
    for (int i = tid; i < HID;  i += 512) h_lds[i]   = h0[i];
    float c = 0.f;
    if (wave == 0 && lane < 8) c = c0[cu * 8 + lane];
    __syncthreads();

    unsigned* myTag = &tags[tid >> 1];   // thread covers h[4t..4t+3] -> producer tid>>1

    for (int t = 0; t < SEQL; ++t) {
        // ---- Eg prefetch (independent of h, overlaps matvec) ----
        float egv = 0.f;
        if (wave == 0)
            egv = Eg[(size_t)seq_lds[t] * 8192 + cu * 32 + d];

        // ---- matvec partial: 128 MACs from registers, h broadcast via LDS ----
        float accv[4] = {0.f, 0.f, 0.f, 0.f};
        const float4* hp = (const float4*)(h_lds + kb);
#define WMAC(i) { float4 hv = hp[i]; \
                  accv[(i)&3] += w##i.x*hv.x + w##i.y*hv.y + w##i.z*hv.z + w##i.w*hv.w; }
        REP32(WMAC)
#undef WMAC
        part[d][wave * 2 + half] = (accv[0] + accv[1]) + (accv[2] + accv[3]);
        __syncthreads();                                   // S1

        // ---- wave 0: reduce, gates, publish ----
        if (wave == 0) {
            float s = 0.f;
#pragma unroll
            for (int i = 0; i < 16; ++i) s += part[d][i];
            float pre = s + egv;
            float act;
            if (d < 24) {                       // f, i, o : sigmoid
                act = 1.f / (1.f + __expf(-pre));
            } else {                            // g : tanh
                float e = __expf(2.f * pre);
                act = 1.f - 2.f / (e + 1.f);
            }
            float iv = __shfl(act, (lane & 7) + 8,  64);
            float ov = __shfl(act, (lane & 7) + 16, 64);
            float gv = __shfl(act, (lane & 7) + 24, 64);
            if (lane < 8) {
                c = act * c + iv * gv;          // act == f on lanes 0..7
                float e2 = __expf(2.f * c);
                float th = 1.f - 2.f / (e2 + 1.f);
                float hn = ov * th;
                Hs[(size_t)t * HID + cu * 8 + lane] = hn;
                hbuf[((t + 1) & 1) * HID + cu * 8 + lane] = hn;
            }
            if (lane == 0)
                __hip_atomic_store(&tags[cu], (unsigned)(t + 1),
                                   __ATOMIC_RELEASE, __HIP_MEMORY_SCOPE_AGENT);
        }

        // ---- dataflow sync: each thread waits only for ITS producer ----
        const unsigned tgt = (unsigned)(t + 1);
        while (__hip_atomic_load(myTag, __ATOMIC_RELAXED,
                                 __HIP_MEMORY_SCOPE_AGENT) < tgt)
            __builtin_amdgcn_s_sleep(1);
        (void)__hip_atomic_load(myTag, __ATOMIC_ACQUIRE,
                                __HIP_MEMORY_SCOPE_AGENT);

        // ---- stage h(t+1) ----
        const float4* hb = (const float4*)(hbuf + ((t + 1) & 1) * HID);
        ((float4*)h_lds)[tid] = hb[tid];
        __syncthreads();                                   // S2
    }

    if (wave == 0 && lane < 8) cfin[cu * 8 + lane] = c;
}

// ---------------------------------------------------------------------------
// Kernel C: preds = Hs @ Wy + by
// ---------------------------------------------------------------------------
__global__ __launch_bounds__(256) void y_gemm(
    const float* __restrict__ Hs, const float* __restrict__ Wy,
    const float* __restrict__ by, float* __restrict__ out)
{
    const int rb  = blockIdx.x * 16;
    const int tid = threadIdx.x;
    __shared__ float A[16][68];
    float acc[16];
#pragma unroll
    for (int r = 0; r < 16; ++r) acc[r] = 0.f;

    for (int k0 = 0; k0 < HID; k0 += 64) {
        __syncthreads();
        for (int i = tid; i < 16 * 64; i += 256) {
            int r = i >> 6, kk = i & 63;
            A[r][kk] = Hs[(size_t)(rb + r) * HID + k0 + kk];
        }
        __syncthreads();
#pragma unroll 8
        for (int kk = 0; kk < 64; ++kk) {
            float b = Wy[(size_t)(k0 + kk) * NCH + tid];
#pragma unroll
            for (int r = 0; r < 16; ++r) acc[r] += A[r][kk] * b;
        }
    }
    float bv = by[tid];
    for (int r = 0; r < 16; ++r)
        out[(size_t)(rb + r) * NCH + tid] = acc[r] + bv;
}

// ---------------------------------------------------------------------------
__global__ void fin_copy(const float* __restrict__ Hs,
                         const float* __restrict__ cfin,
                         float* __restrict__ out)
{
    int i = blockIdx.x * 256 + threadIdx.x;
    if (i < HID)
        out[(size_t)SEQL * NCH + i] = Hs[(size_t)(SEQL - 1) * HID + i];
    else
        out[(size_t)SEQL * NCH + i] = cfin[i - HID];
}

// ---------------------------------------------------------------------------
extern "C" void kernel_launch(void* const* d_in, const int* in_sizes, int n_in,
                              void* d_out, int out_size, void* d_ws, size_t ws_size,
                              hipStream_t stream)
{
    if (n_in < 14 || ws_size < WS_NEED) return;

    const int*   seq = (const int*)  d_in[0];
    const float* h0  = (const float*)d_in[1];
    const float* c0  = (const float*)d_in[2];
    const float* emb = (const float*)d_in[3];
    const float* Wf  = (const float*)d_in[4];
    const float* bf  = (const float*)d_in[5];
    const float* Wi  = (const float*)d_in[6];
    const float* bi  = (const float*)d_in[7];
    const float* Wo  = (const float*)d_in[8];
    const float* bo  = (const float*)d_in[9];
    const float* Wc  = (const float*)d_in[10];
    const float* bc  = (const float*)d_in[11];
    const float* Wy  = (const float*)d_in[12];
    const float* by  = (const float*)d_in[13];

    char* ws = (char*)d_ws;
    float*    Eg   = (float*)(ws + EG_OFF);
    float*    Hs   = (float*)(ws + HS_OFF);
    float*    hbuf = (float*)(ws + HB_OFF);
    float*    cfin = (float*)(ws + CF_OFF);
    unsigned* tags = (unsigned*)(ws + CT_OFF);
    float*    out  = (float*)d_out;

    hipMemsetAsync(tags, 0, CT_BYTES, stream);

    eg_gemm<<<256, 256, 0, stream>>>(emb, Wf, bf, Wi, bi, Wo, bo, Wc, bc, Eg);

    lstm_seq<<<256, 512, 0, stream>>>(seq, h0, c0, Wf, Wi, Wo, Wc, Eg,
                                      Hs, hbuf, cfin, tags);

    y_gemm<<<256, 256, 0, stream>>>(Hs, Wy, by, out);

    fin_copy<<<16, 256, 0, stream>>>(Hs, cfin, out);
}

// Round 4
// 96033.618 us; speedup vs baseline: 1.0085x; 1.0070x over previous
//
#include <hip/hip_runtime.h>
#include <hip/hip_bf16.h>
#include <stdint.h>

#define NCH  256
#define EMB  1024
#define HID  2048
#define SEQL 4096

// ---------------- ws layout (bytes) ----------------
static constexpr size_t EG_OFF   = 0;
static constexpr size_t EG_BYTES = (size_t)NCH * 8192 * 4;          // 8,388,608
static constexpr size_t HS_OFF   = EG_OFF + EG_BYTES;
static constexpr size_t HS_BYTES = (size_t)SEQL * HID * 4;          // 33,554,432
static constexpr size_t HB_OFF   = HS_OFF + HS_BYTES;
static constexpr size_t HB_BYTES = 2 * HID * 4;
static constexpr size_t CF_OFF   = HB_OFF + HB_BYTES;
static constexpr size_t CF_BYTES = HID * 4;
static constexpr size_t CT_OFF   = CF_OFF + CF_BYTES;
static constexpr size_t CT_BYTES = 4096;                             // tags[256] + slack
static constexpr size_t WS_NEED  = CT_OFF + CT_BYTES;

// ---------------------------------------------------------------------------
// Kernel A: Eg[c][cu*32 + gate*8 + jl] = bias_g[j] + sum_e emb[c][e]*Wg[e][j]
// ---------------------------------------------------------------------------
__global__ __launch_bounds__(256) void eg_gemm(
    const float* __restrict__ emb,
    const float* __restrict__ Wf, const float* __restrict__ bf,
    const float* __restrict__ Wi, const float* __restrict__ bi,
    const float* __restrict__ Wo, const float* __restrict__ bo,
    const float* __restrict__ Wc, const float* __restrict__ bc,
    float* __restrict__ Eg)
{
    const int nb  = blockIdx.x & 63;
    const int cb  = blockIdx.x >> 6;
    const int tid = threadIdx.x;
    const int col = tid & 127;
    const int gate = col >> 5;
    const int jj   = col & 31;
    const int j    = nb * 32 + jj;
    const int mh   = tid >> 7;

    __shared__ float embT[32][65];
    __shared__ float Wt[32][128];

    float acc[32];
#pragma unroll
    for (int m = 0; m < 32; ++m) acc[m] = 0.f;

    for (int k0 = 0; k0 < EMB; k0 += 32) {
        __syncthreads();
        for (int i = tid; i < 64 * 32; i += 256) {
            int c = i >> 5, kk = i & 31;
            embT[kk][c] = emb[(size_t)(cb * 64 + c) * EMB + k0 + kk];
        }
        for (int i = tid; i < 32 * 128; i += 256) {
            int kk = i >> 7, cl = i & 127;
            int g2 = cl >> 5;
            int jx = nb * 32 + (cl & 31);
            const float* Wp = (g2 == 0) ? Wf : (g2 == 1) ? Wi : (g2 == 2) ? Wo : Wc;
            Wt[kk][cl] = Wp[(size_t)(k0 + kk) * HID + jx];
        }
        __syncthreads();
#pragma unroll 8
        for (int kk = 0; kk < 32; ++kk) {
            float w = Wt[kk][col];
#pragma unroll
            for (int m = 0; m < 32; ++m)
                acc[m] += embT[kk][mh * 32 + m] * w;
        }
    }
    const float* bias = (gate == 0) ? bf : (gate == 1) ? bi : (gate == 2) ? bo : bc;
    float bv = bias[j];
    for (int m = 0; m < 32; ++m) {
        int c = cb * 64 + mh * 32 + m;
        Eg[(size_t)c * 8192 + (j >> 3) * 32 + gate * 8 + (j & 7)] = acc[m] + bv;
    }
}

// ---------------------------------------------------------------------------
// Kernel B: persistent sequential LSTM, flag-based dataflow sync (no barrier).
// 256 WGs (1/CU) x 512 threads. Weights: 32 NAMED float4 per thread (forced
// register residency). Per step:
//   all: matvec partials -> S1 -> wave0: reduce+gates, publish h + tag[cu]
//   all: poll own tag, acquire, stage h float4 -> S2
// ---------------------------------------------------------------------------
#define REP32(M) M(0) M(1) M(2) M(3) M(4) M(5) M(6) M(7) M(8) M(9) M(10) M(11) \
  M(12) M(13) M(14) M(15) M(16) M(17) M(18) M(19) M(20) M(21) M(22) M(23)      \
  M(24) M(25) M(26) M(27) M(28) M(29) M(30) M(31)

__global__ __launch_bounds__(512, 2) void lstm_seq(
    const int*   __restrict__ seq,
    const float* __restrict__ h0,
    const float* __restrict__ c0,
    const float* __restrict__ Wf, const float* __restrict__ Wi,
    const float* __restrict__ Wo, const float* __restrict__ Wc,
    const float* __restrict__ Eg,
    float* __restrict__ Hs,
    float* hbuf, float* cfin, unsigned* tags)
{
    const int cu   = blockIdx.x;      // 0..255
    const int tid  = threadIdx.x;     // 0..511
    const int lane = tid & 63;
    const int wave = tid >> 6;        // 0..7
    const int d    = lane & 31;       // dot index within CU (gate*8 + jl)
    const int half = lane >> 5;       // k half
    const int gate = d >> 3;
    const int jl   = d & 7;
    const int j    = cu * 8 + jl;
    const int kb   = wave * 256 + half * 128;

    const float* W = (gate == 0) ? Wf : (gate == 1) ? Wi : (gate == 2) ? Wo : Wc;

    // ---- 128 recurrent weights in NAMED registers ----
    const float* Wb = W + (size_t)(1024 + kb) * HID + j;
#define WDECL(i) float4 w##i;
    REP32(WDECL)
#undef WDECL
#define WLOAD(i) { w##i.x = Wb[(size_t)(4*i+0)*HID]; \
                   w##i.y = Wb[(size_t)(4*i+1)*HID]; \
                   w##i.z = Wb[(size_t)(4*i+2)*HID]; \
                   w##i.w = Wb[(size_t)(4*i+3)*HID]; }
    REP32(WLOAD)
#undef WLOAD

    __shared__ __align__(16) float h_lds[HID];
    __shared__ float part[32][17];
    __shared__ int   seq_lds[SEQL];   // 16 KB

    for (int i = tid; i < SEQL; i += 512) seq_lds[i] = seq[i];
    for (int i = tid; i < HID;  i += 512) h_lds[i]   = h0[i];
    float c = 0.f;
    if (wave == 0 && lane < 8) c = c0[cu * 8 + lane];
    __syncthreads();

    unsigned* myTag = &tags[tid >> 1];   // thread covers h[4t..4t+3] -> producer tid>>1

    for (int t = 0; t < SEQL; ++t) {
        // ---- Eg prefetch (independent of h, overlaps matvec) ----
        float egv = 0.f;
        if (wave == 0)
            egv = Eg[(size_t)seq_lds[t] * 8192 + cu * 32 + d];

        // ---- matvec partial: 128 MACs from registers, h broadcast via LDS ----
        float accv[4] = {0.f, 0.f, 0.f, 0.f};
        const float4* hp = (const float4*)(h_lds + kb);
#define WMAC(i) { float4 hv = hp[i]; \
                  accv[(i)&3] += w##i.x*hv.x + w##i.y*hv.y + w##i.z*hv.z + w##i.w*hv.w; }
        REP32(WMAC)
#undef WMAC
        part[d][wave * 2 + half] = (accv[0] + accv[1]) + (accv[2] + accv[3]);
        __syncthreads();                                   // S1

        // ---- wave 0: reduce, gates, publish ----
        if (wave == 0) {
            float s = 0.f;
#pragma unroll
            for (int i = 0; i < 16; ++i) s += part[d][i];
            float pre = s + egv;
            float act;
            if (d < 24) {                       // f, i, o : sigmoid
                act = 1.f / (1.f + __expf(-pre));
            } else {                            // g : tanh
                float e = __expf(2.f * pre);
                act = 1.f - 2.f / (e + 1.f);
            }
            float iv = __shfl(act, (lane & 7) + 8,  64);
            float ov = __shfl(act, (lane & 7) + 16, 64);
            float gv = __shfl(act, (lane & 7) + 24, 64);
            if (lane < 8) {
                c = act * c + iv * gv;          // act == f on lanes 0..7
                float e2 = __expf(2.f * c);
                float th = 1.f - 2.f / (e2 + 1.f);
                float hn = ov * th;
                Hs[(size_t)t * HID + cu * 8 + lane] = hn;
                hbuf[((t + 1) & 1) * HID + cu * 8 + lane] = hn;
            }
            if (lane == 0)
                __hip_atomic_store(&tags[cu], (unsigned)(t + 1),
                                   __ATOMIC_RELEASE, __HIP_MEMORY_SCOPE_AGENT);
        }

        // ---- dataflow sync: each thread waits only for ITS producer ----
        const unsigned tgt = (unsigned)(t + 1);
        while (__hip_atomic_load(myTag, __ATOMIC_RELAXED,
                                 __HIP_MEMORY_SCOPE_AGENT) < tgt)
            __builtin_amdgcn_s_sleep(1);
        (void)__hip_atomic_load(myTag, __ATOMIC_ACQUIRE,
                                __HIP_MEMORY_SCOPE_AGENT);

        // ---- stage h(t+1) ----
        const float4* hb = (const float4*)(hbuf + ((t + 1) & 1) * HID);
        ((float4*)h_lds)[tid] = hb[tid];
        __syncthreads();                                   // S2
    }

    if (wave == 0 && lane < 8) cfin[cu * 8 + lane] = c;
}

// ---------------------------------------------------------------------------
// Kernel C: preds = Hs @ Wy + by
// ---------------------------------------------------------------------------
__global__ __launch_bounds__(256) void y_gemm(
    const float* __restrict__ Hs, const float* __restrict__ Wy,
    const float* __restrict__ by, float* __restrict__ out)
{
    const int rb  = blockIdx.x * 16;
    const int tid = threadIdx.x;
    __shared__ float A[16][68];
    float acc[16];
#pragma unroll
    for (int r = 0; r < 16; ++r) acc[r] = 0.f;

    for (int k0 = 0; k0 < HID; k0 += 64) {
        __syncthreads();
        for (int i = tid; i < 16 * 64; i += 256) {
            int r = i >> 6, kk = i & 63;
            A[r][kk] = Hs[(size_t)(rb + r) * HID + k0 + kk];
        }
        __syncthreads();
#pragma unroll 8
        for (int kk = 0; kk < 64; ++kk) {
            float b = Wy[(size_t)(k0 + kk) * NCH + tid];
#pragma unroll
            for (int r = 0; r < 16; ++r) acc[r] += A[r][kk] * b;
        }
    }
    float bv = by[tid];
    for (int r = 0; r < 16; ++r)
        out[(size_t)(rb + r) * NCH + tid] = acc[r] + bv;
}

// ---------------------------------------------------------------------------
__global__ void fin_copy(const float* __restrict__ Hs,
                         const float* __restrict__ cfin,
                         float* __restrict__ out)
{
    int i = blockIdx.x * 256 + threadIdx.x;
    if (i < HID)
        out[(size_t)SEQL * NCH + i] = Hs[(size_t)(SEQL - 1) * HID + i];
    else
        out[(size_t)SEQL * NCH + i] = cfin[i - HID];
}

// ---------------------------------------------------------------------------
extern "C" void kernel_launch(void* const* d_in, const int* in_sizes, int n_in,
                              void* d_out, int out_size, void* d_ws, size_t ws_size,
                              hipStream_t stream)
{
    if (n_in < 14 || ws_size < WS_NEED) return;

    const int*   seq = (const int*)  d_in[0];
    const float* h0  = (const float*)d_in[1];
    const float* c0  = (const float*)d_in[2];
    const float* emb = (const float*)d_in[3];
    const float* Wf  = (const float*)d_in[4];
    const float* bf  = (const float*)d_in[5];
    const float* Wi  = (const float*)d_in[6];
    const float* bi  = (const float*)d_in[7];
    const float* Wo  = (const float*)d_in[8];
    const float* bo  = (const float*)d_in[9];
    const float* Wc  = (const float*)d_in[10];
    const float* bc  = (const float*)d_in[11];
    const float* Wy  = (const float*)d_in[12];
    const float* by  = (const float*)d_in[13];

    char* ws = (char*)d_ws;
    float*    Eg   = (float*)(ws + EG_OFF);
    float*    Hs   = (float*)(ws + HS_OFF);
    float*    hbuf = (float*)(ws + HB_OFF);
    float*    cfin = (float*)(ws + CF_OFF);
    unsigned* tags = (unsigned*)(ws + CT_OFF);
    float*    out  = (float*)d_out;

    hipMemsetAsync(tags, 0, CT_BYTES, stream);

    eg_gemm<<<256, 256, 0, stream>>>(emb, Wf, bf, Wi, bi, Wo, bo, Wc, bc, Eg);

    lstm_seq<<<256, 512, 0, stream>>>(seq, h0, c0, Wf, Wi, Wo, Wc, Eg,
                                      Hs, hbuf, cfin, tags);

    y_gemm<<<256, 256, 0, stream>>>(Hs, Wy, by, out);

    fin_copy<<<16, 256, 0, stream>>>(Hs, cfin, out);
}

// Round 5
// 95072.430 us; speedup vs baseline: 1.0187x; 1.0101x over previous
//
#include <hip/hip_runtime.h>
#include <hip/hip_bf16.h>
#include <stdint.h>

#define NCH  256
#define EMB  1024
#define HID  2048
#define SEQL 4096

// ---------------- ws layout (bytes) ----------------
static constexpr size_t EG_OFF   = 0;
static constexpr size_t EG_BYTES = (size_t)NCH * 8192 * 4;          // 8,388,608
static constexpr size_t HS_OFF   = EG_OFF + EG_BYTES;
static constexpr size_t HS_BYTES = (size_t)SEQL * HID * 4;          // 33,554,432
static constexpr size_t HB_OFF   = HS_OFF + HS_BYTES;
static constexpr size_t HB_BYTES = 2 * HID * 4;
static constexpr size_t CF_OFF   = HB_OFF + HB_BYTES;
static constexpr size_t CF_BYTES = HID * 4;
static constexpr size_t CT_OFF   = CF_OFF + CF_BYTES;
static constexpr size_t CT_BYTES = 4096;                             // tags[256] + slack
static constexpr size_t WS_NEED  = CT_OFF + CT_BYTES;

// ---------------------------------------------------------------------------
// Kernel A: Eg[c][cu*32 + gate*8 + jl] = bias_g[j] + sum_e emb[c][e]*Wg[e][j]
// ---------------------------------------------------------------------------
__global__ __launch_bounds__(256) void eg_gemm(
    const float* __restrict__ emb,
    const float* __restrict__ Wf, const float* __restrict__ bf,
    const float* __restrict__ Wi, const float* __restrict__ bi,
    const float* __restrict__ Wo, const float* __restrict__ bo,
    const float* __restrict__ Wc, const float* __restrict__ bc,
    float* __restrict__ Eg)
{
    const int nb  = blockIdx.x & 63;
    const int cb  = blockIdx.x >> 6;
    const int tid = threadIdx.x;
    const int col = tid & 127;
    const int gate = col >> 5;
    const int jj   = col & 31;
    const int j    = nb * 32 + jj;
    const int mh   = tid >> 7;

    __shared__ float embT[32][65];
    __shared__ float Wt[32][128];

    float acc[32];
#pragma unroll
    for (int m = 0; m < 32; ++m) acc[m] = 0.f;

    for (int k0 = 0; k0 < EMB; k0 += 32) {
        __syncthreads();
        for (int i = tid; i < 64 * 32; i += 256) {
            int c = i >> 5, kk = i & 31;
            embT[kk][c] = emb[(size_t)(cb * 64 + c) * EMB + k0 + kk];
        }
        for (int i = tid; i < 32 * 128; i += 256) {
            int kk = i >> 7, cl = i & 127;
            int g2 = cl >> 5;
            int jx = nb * 32 + (cl & 31);
            const float* Wp = (g2 == 0) ? Wf : (g2 == 1) ? Wi : (g2 == 2) ? Wo : Wc;
            Wt[kk][cl] = Wp[(size_t)(k0 + kk) * HID + jx];
        }
        __syncthreads();
#pragma unroll 8
        for (int kk = 0; kk < 32; ++kk) {
            float w = Wt[kk][col];
#pragma unroll
            for (int m = 0; m < 32; ++m)
                acc[m] += embT[kk][mh * 32 + m] * w;
        }
    }
    const float* bias = (gate == 0) ? bf : (gate == 1) ? bi : (gate == 2) ? bo : bc;
    float bv = bias[j];
    for (int m = 0; m < 32; ++m) {
        int c = cb * 64 + mh * 32 + m;
        Eg[(size_t)c * 8192 + (j >> 3) * 32 + gate * 8 + (j & 7)] = acc[m] + bv;
    }
}

// ---------------------------------------------------------------------------
// Kernel B: persistent sequential LSTM, flag-based dataflow sync (no barrier).
// 256 WGs (1/CU) x 512 threads. Weights: 32 NAMED float4 per thread (forced
// register residency). Per step:
//   all: matvec partials -> S1 -> wave0: reduce+gates, publish h + tag[cu]
//   all: poll own tag, acquire, stage h float4 -> S2
// ---------------------------------------------------------------------------
#define REP32(M) M(0) M(1) M(2) M(3) M(4) M(5) M(6) M(7) M(8) M(9) M(10) M(11) \
  M(12) M(13) M(14) M(15) M(16) M(17) M(18) M(19) M(20) M(21) M(22) M(23)      \
  M(24) M(25) M(26) M(27) M(28) M(29) M(30) M(31)

__global__ __launch_bounds__(512, 2) void lstm_seq(
    const int*   __restrict__ seq,
    const float* __restrict__ h0,
    const float* __restrict__ c0,
    const float* __restrict__ Wf, const float* __restrict__ Wi,
    const float* __restrict__ Wo, const float* __restrict__ Wc,
    const float* __restrict__ Eg,
    float* __restrict__ Hs,
    float* hbuf, float* cfin, unsigned* tags)
{
    const int cu   = blockIdx.x;      // 0..255
    const int tid  = threadIdx.x;     // 0..511
    const int lane = tid & 63;
    const int wave = tid >> 6;        // 0..7
    const int d    = lane & 31;       // dot index within CU (gate*8 + jl)
    const int half = lane >> 5;       // k half
    const int gate = d >> 3;
    const int jl   = d & 7;
    const int j    = cu * 8 + jl;
    const int kb   = wave * 256 + half * 128;

    const float* W = (gate == 0) ? Wf : (gate == 1) ? Wi : (gate == 2) ? Wo : Wc;

    // ---- 128 recurrent weights in NAMED registers ----
    const float* Wb = W + (size_t)(1024 + kb) * HID + j;
#define WDECL(i) float4 w##i;
    REP32(WDECL)
#undef WDECL
#define WLOAD(i) { w##i.x = Wb[(size_t)(4*i+0)*HID]; \
                   w##i.y = Wb[(size_t)(4*i+1)*HID]; \
                   w##i.z = Wb[(size_t)(4*i+2)*HID]; \
                   w##i.w = Wb[(size_t)(4*i+3)*HID]; }
    REP32(WLOAD)
#undef WLOAD

    __shared__ __align__(16) float h_lds[HID];
    __shared__ float part[32][17];
    __shared__ int   seq_lds[SEQL];   // 16 KB

    for (int i = tid; i < SEQL; i += 512) seq_lds[i] = seq[i];
    for (int i = tid; i < HID;  i += 512) h_lds[i]   = h0[i];
    float c = 0.f;
    if (wave == 0 && lane < 8) c = c0[cu * 8 + lane];
    __syncthreads();

    unsigned* myTag = &tags[tid >> 1];   // thread covers h[4t..4t+3] -> producer tid>>1

    for (int t = 0; t < SEQL; ++t) {
        // ---- Eg prefetch (independent of h, overlaps matvec) ----
        float egv = 0.f;
        if (wave == 0)
            egv = Eg[(size_t)seq_lds[t] * 8192 + cu * 32 + d];

        // ---- matvec partial: 128 MACs from registers, h broadcast via LDS ----
        float accv[4] = {0.f, 0.f, 0.f, 0.f};
        const float4* hp = (const float4*)(h_lds + kb);
#define WMAC(i) { float4 hv = hp[i]; \
                  accv[(i)&3] += w##i.x*hv.x + w##i.y*hv.y + w##i.z*hv.z + w##i.w*hv.w; }
        REP32(WMAC)
#undef WMAC
        part[d][wave * 2 + half] = (accv[0] + accv[1]) + (accv[2] + accv[3]);
        __syncthreads();                                   // S1

        // ---- wave 0: reduce, gates, publish ----
        if (wave == 0) {
            float s = 0.f;
#pragma unroll
            for (int i = 0; i < 16; ++i) s += part[d][i];
            float pre = s + egv;
            float act;
            if (d < 24) {                       // f, i, o : sigmoid
                act = 1.f / (1.f + __expf(-pre));
            } else {                            // g : tanh
                float e = __expf(2.f * pre);
                act = 1.f - 2.f / (e + 1.f);
            }
            float iv = __shfl(act, (lane & 7) + 8,  64);
            float ov = __shfl(act, (lane & 7) + 16, 64);
            float gv = __shfl(act, (lane & 7) + 24, 64);
            if (lane < 8) {
                c = act * c + iv * gv;          // act == f on lanes 0..7
                float e2 = __expf(2.f * c);
                float th = 1.f - 2.f / (e2 + 1.f);
                float hn = ov * th;
                Hs[(size_t)t * HID + cu * 8 + lane] = hn;
                hbuf[((t + 1) & 1) * HID + cu * 8 + lane] = hn;
            }
            if (lane == 0)
                __hip_atomic_store(&tags[cu], (unsigned)(t + 1),
                                   __ATOMIC_RELEASE, __HIP_MEMORY_SCOPE_AGENT);
        }

        // ---- dataflow sync: each thread waits only for ITS producer ----
        const unsigned tgt = (unsigned)(t + 1);
        while (__hip_atomic_load(myTag, __ATOMIC_RELAXED,
                                 __HIP_MEMORY_SCOPE_AGENT) < tgt)
            __builtin_amdgcn_s_sleep(1);
        (void)__hip_atomic_load(myTag, __ATOMIC_ACQUIRE,
                                __HIP_MEMORY_SCOPE_AGENT);

        // ---- stage h(t+1) ----
        const float4* hb = (const float4*)(hbuf + ((t + 1) & 1) * HID);
        ((float4*)h_lds)[tid] = hb[tid];
        __syncthreads();                                   // S2
    }

    if (wave == 0 && lane < 8) cfin[cu * 8 + lane] = c;
}

// ---------------------------------------------------------------------------
// Kernel C: preds = Hs @ Wy + by
// ---------------------------------------------------------------------------
__global__ __launch_bounds__(256) void y_gemm(
    const float* __restrict__ Hs, const float* __restrict__ Wy,
    const float* __restrict__ by, float* __restrict__ out)
{
    const int rb  = blockIdx.x * 16;
    const int tid = threadIdx.x;
    __shared__ float A[16][68];
    float acc[16];
#pragma unroll
    for (int r = 0; r < 16; ++r) acc[r] = 0.f;

    for (int k0 = 0; k0 < HID; k0 += 64) {
        __syncthreads();
        for (int i = tid; i < 16 * 64; i += 256) {
            int r = i >> 6, kk = i & 63;
            A[r][kk] = Hs[(size_t)(rb + r) * HID + k0 + kk];
        }
        __syncthreads();
#pragma unroll 8
        for (int kk = 0; kk < 64; ++kk) {
            float b = Wy[(size_t)(k0 + kk) * NCH + tid];
#pragma unroll
            for (int r = 0; r < 16; ++r) acc[r] += A[r][kk] * b;
        }
    }
    float bv = by[tid];
    for (int r = 0; r < 16; ++r)
        out[(size_t)(rb + r) * NCH + tid] = acc[r] + bv;
}

// ---------------------------------------------------------------------------
__global__ void fin_copy(const float* __restrict__ Hs,
                         const float* __restrict__ cfin,
                         float* __restrict__ out)
{
    int i = blockIdx.x * 256 + threadIdx.x;
    if (i < HID)
        out[(size_t)SEQL * NCH + i] = Hs[(size_t)(SEQL - 1) * HID + i];
    else
        out[(size_t)SEQL * NCH + i] = cfin[i - HID];
}

// ---------------------------------------------------------------------------
extern "C" void kernel_launch(void* const* d_in, const int* in_sizes, int n_in,
                              void* d_out, int out_size, void* d_ws, size_t ws_size,
                              hipStream_t stream)
{
    if (n_in < 14 || ws_size < WS_NEED) return;

    const int*   seq = (const int*)  d_in[0];
    const float* h0  = (const float*)d_in[1];
    const float* c0  = (const float*)d_in[2];
    const float* emb = (const float*)d_in[3];
    const float* Wf  = (const float*)d_in[4];
    const float* bf  = (const float*)d_in[5];
    const float* Wi  = (const float*)d_in[6];
    const float* bi  = (const float*)d_in[7];
    const float* Wo  = (const float*)d_in[8];
    const float* bo  = (const float*)d_in[9];
    const float* Wc  = (const float*)d_in[10];
    const float* bc  = (const float*)d_in[11];
    const float* Wy  = (const float*)d_in[12];
    const float* by  = (const float*)d_in[13];

    char* ws = (char*)d_ws;
    float*    Eg   = (float*)(ws + EG_OFF);
    float*    Hs   = (float*)(ws + HS_OFF);
    float*    hbuf = (float*)(ws + HB_OFF);
    float*    cfin = (float*)(ws + CF_OFF);
    unsigned* tags = (unsigned*)(ws + CT_OFF);
    float*    out  = (float*)d_out;

    hipMemsetAsync(tags, 0, CT_BYTES, stream);

    eg_gemm<<<256, 256, 0, stream>>>(emb, Wf, bf, Wi, bi, Wo, bo, Wc, bc, Eg);

    lstm_seq<<<256, 512, 0, stream>>>(seq, h0, c0, Wf, Wi, Wo, Wc, Eg,
                                      Hs, hbuf, cfin, tags);

    y_gemm<<<256, 256, 0, stream>>>(Hs, Wy, by, out);

    fin_copy<<<16, 256, 0, stream>>>(Hs, cfin, out);
}

// Round 6
// 24854.726 us; speedup vs baseline: 3.8966x; 3.8251x over previous
//
#include <hip/hip_runtime.h>
#include <hip/hip_bf16.h>
#include <stdint.h>

#define NCH  256
#define EMB  1024
#define HID  2048
#define SEQL 4096

// ---------------- ws layout (bytes) ----------------
static constexpr size_t EG_OFF   = 0;
static constexpr size_t EG_BYTES = (size_t)NCH * 8192 * 4;          // 8,388,608
static constexpr size_t HS_OFF   = EG_OFF + EG_BYTES;
static constexpr size_t HS_BYTES = (size_t)SEQL * HID * 4;          // 33,554,432
static constexpr size_t HB_OFF   = HS_OFF + HS_BYTES;
static constexpr size_t HB_BYTES = 2 * HID * 4;
static constexpr size_t CF_OFF   = HB_OFF + HB_BYTES;
static constexpr size_t CF_BYTES = HID * 4;
static constexpr size_t CT_OFF   = CF_OFF + CF_BYTES;
static constexpr size_t CT_BYTES = 4096;                             // tags[256] + slack
static constexpr size_t WS_NEED  = CT_OFF + CT_BYTES;

// ---------------------------------------------------------------------------
// Kernel A: Eg[c][cu*32 + gate*8 + jl] = bias_g[j] + sum_e emb[c][e]*Wg[e][j]
// ---------------------------------------------------------------------------
__global__ __launch_bounds__(256) void eg_gemm(
    const float* __restrict__ emb,
    const float* __restrict__ Wf, const float* __restrict__ bf,
    const float* __restrict__ Wi, const float* __restrict__ bi,
    const float* __restrict__ Wo, const float* __restrict__ bo,
    const float* __restrict__ Wc, const float* __restrict__ bc,
    float* __restrict__ Eg)
{
    const int nb  = blockIdx.x & 63;
    const int cb  = blockIdx.x >> 6;
    const int tid = threadIdx.x;
    const int col = tid & 127;
    const int gate = col >> 5;
    const int jj   = col & 31;
    const int j    = nb * 32 + jj;
    const int mh   = tid >> 7;

    __shared__ float embT[32][65];
    __shared__ float Wt[32][128];

    float acc[32];
#pragma unroll
    for (int m = 0; m < 32; ++m) acc[m] = 0.f;

    for (int k0 = 0; k0 < EMB; k0 += 32) {
        __syncthreads();
        for (int i = tid; i < 64 * 32; i += 256) {
            int c = i >> 5, kk = i & 31;
            embT[kk][c] = emb[(size_t)(cb * 64 + c) * EMB + k0 + kk];
        }
        for (int i = tid; i < 32 * 128; i += 256) {
            int kk = i >> 7, cl = i & 127;
            int g2 = cl >> 5;
            int jx = nb * 32 + (cl & 31);
            const float* Wp = (g2 == 0) ? Wf : (g2 == 1) ? Wi : (g2 == 2) ? Wo : Wc;
            Wt[kk][cl] = Wp[(size_t)(k0 + kk) * HID + jx];
        }
        __syncthreads();
#pragma unroll 8
        for (int kk = 0; kk < 32; ++kk) {
            float w = Wt[kk][col];
#pragma unroll
            for (int m = 0; m < 32; ++m)
                acc[m] += embT[kk][mh * 32 + m] * w;
        }
    }
    const float* bias = (gate == 0) ? bf : (gate == 1) ? bi : (gate == 2) ? bo : bc;
    float bv = bias[j];
    for (int m = 0; m < 32; ++m) {
        int c = cb * 64 + mh * 32 + m;
        Eg[(size_t)c * 8192 + (j >> 3) * 32 + gate * 8 + (j & 7)] = acc[m] + bv;
    }
}

// ---------------------------------------------------------------------------
// Kernel B: persistent sequential LSTM.
// Cross-CU exchange built ENTIRELY from relaxed agent-scope atomics (sc0/sc1
// per-access L1/L2 bypass -> coherent via L3). No acquire/release fences =>
// no buffer_inv / buffer_wbl2 in the loop (R5's 2.3x regression was 512
// L2-invalidates per CU per step). Producer ordering: data stores ->
// s_waitcnt vmcnt(0) -> tag store. Consumer ordering: control dep on tag
// poll + compiler barrier, then relaxed data loads.
// ---------------------------------------------------------------------------
#define REP32(M) M(0) M(1) M(2) M(3) M(4) M(5) M(6) M(7) M(8) M(9) M(10) M(11) \
  M(12) M(13) M(14) M(15) M(16) M(17) M(18) M(19) M(20) M(21) M(22) M(23)      \
  M(24) M(25) M(26) M(27) M(28) M(29) M(30) M(31)

__global__ __launch_bounds__(512, 2) void lstm_seq(
    const int*   __restrict__ seq,
    const float* __restrict__ h0,
    const float* __restrict__ c0,
    const float* __restrict__ Wf, const float* __restrict__ Wi,
    const float* __restrict__ Wo, const float* __restrict__ Wc,
    const float* __restrict__ Eg,
    float* __restrict__ Hs,
    float* hbuf, float* cfin, unsigned* tags)
{
    const int cu   = blockIdx.x;      // 0..255
    const int tid  = threadIdx.x;     // 0..511
    const int lane = tid & 63;
    const int wave = tid >> 6;        // 0..7
    const int d    = lane & 31;       // dot index within CU (gate*8 + jl)
    const int half = lane >> 5;       // k half
    const int gate = d >> 3;
    const int jl   = d & 7;
    const int j    = cu * 8 + jl;
    const int kb   = wave * 256 + half * 128;

    const float* W = (gate == 0) ? Wf : (gate == 1) ? Wi : (gate == 2) ? Wo : Wc;

    // ---- 128 recurrent weights in named registers (VGPR/AGPR resident) ----
    const float* Wb = W + (size_t)(1024 + kb) * HID + j;
#define WDECL(i) float4 w##i;
    REP32(WDECL)
#undef WDECL
#define WLOAD(i) { w##i.x = Wb[(size_t)(4*i+0)*HID]; \
                   w##i.y = Wb[(size_t)(4*i+1)*HID]; \
                   w##i.z = Wb[(size_t)(4*i+2)*HID]; \
                   w##i.w = Wb[(size_t)(4*i+3)*HID]; }
    REP32(WLOAD)
#undef WLOAD

    __shared__ __align__(16) float h_lds[HID];
    __shared__ float part[32][17];
    __shared__ int   seq_lds[SEQL];   // 16 KB

    for (int i = tid; i < SEQL; i += 512) seq_lds[i] = seq[i];
    for (int i = tid; i < HID;  i += 512) h_lds[i]   = h0[i];
    float c = 0.f;
    if (wave == 0 && lane < 8) c = c0[cu * 8 + lane];
    __syncthreads();

    unsigned* myTag = &tags[tid >> 1];   // producer of h[4*tid .. 4*tid+3]
    unsigned* hbw   = (unsigned*)hbuf;

    for (int t = 0; t < SEQL; ++t) {
        // ---- Eg prefetch (independent of h, overlaps matvec) ----
        float egv = 0.f;
        if (wave == 0)
            egv = Eg[(size_t)seq_lds[t] * 8192 + cu * 32 + d];

        // ---- matvec partial: 128 MACs from registers, h via LDS ----
        float accv[4] = {0.f, 0.f, 0.f, 0.f};
        const float4* hp = (const float4*)(h_lds + kb);
#define WMAC(i) { float4 hv = hp[i]; \
                  accv[(i)&3] += w##i.x*hv.x + w##i.y*hv.y + w##i.z*hv.z + w##i.w*hv.w; }
        REP32(WMAC)
#undef WMAC
        part[d][wave * 2 + half] = (accv[0] + accv[1]) + (accv[2] + accv[3]);
        __syncthreads();                                   // S1

        const unsigned tgt = (unsigned)(t + 1);
        const unsigned bsel = (unsigned)((t + 1) & 1);

        // ---- wave 0: reduce, gates, publish (relaxed stores + vmcnt) ----
        if (wave == 0) {
            float s = 0.f;
#pragma unroll
            for (int i = 0; i < 16; ++i) s += part[d][i];
            float pre = s + egv;
            float act;
            if (d < 24) {                       // f, i, o : sigmoid
                act = 1.f / (1.f + __expf(-pre));
            } else {                            // g : tanh
                float e = __expf(2.f * pre);
                act = 1.f - 2.f / (e + 1.f);
            }
            float iv = __shfl(act, (lane & 7) + 8,  64);
            float ov = __shfl(act, (lane & 7) + 16, 64);
            float gv = __shfl(act, (lane & 7) + 24, 64);
            float hn = 0.f;
            if (lane < 8) {
                c = act * c + iv * gv;          // act == f on lanes 0..7
                float e2 = __expf(2.f * c);
                float th = 1.f - 2.f / (e2 + 1.f);
                hn = ov * th;
                __hip_atomic_store(&hbw[bsel * HID + cu * 8 + lane],
                                   __float_as_uint(hn),
                                   __ATOMIC_RELAXED, __HIP_MEMORY_SCOPE_AGENT);
            }
            // data stores globally visible (sc1 -> L3) before tag store
            asm volatile("s_waitcnt vmcnt(0)" ::: "memory");
            if (lane == 0)
                __hip_atomic_store(&tags[cu], tgt,
                                   __ATOMIC_RELAXED, __HIP_MEMORY_SCOPE_AGENT);
            // Hs store off the critical path
            if (lane < 8)
                Hs[(size_t)t * HID + cu * 8 + lane] = hn;
        }

        // ---- dataflow sync: poll ONLY this thread's producer tag ----
        if (__hip_atomic_load(myTag, __ATOMIC_RELAXED,
                              __HIP_MEMORY_SCOPE_AGENT) < tgt) {
            do {
                __builtin_amdgcn_s_sleep(1);
            } while (__hip_atomic_load(myTag, __ATOMIC_RELAXED,
                                       __HIP_MEMORY_SCOPE_AGENT) < tgt);
        }
        asm volatile("" ::: "memory");          // keep data loads below poll
        __builtin_amdgcn_sched_barrier(0);

        // ---- stage this thread's 4 h values (relaxed, L3-coherent) ----
        {
            const unsigned* hb = hbw + bsel * HID + 4 * tid;
            unsigned v0 = __hip_atomic_load(&hb[0], __ATOMIC_RELAXED,
                                            __HIP_MEMORY_SCOPE_AGENT);
            unsigned v1 = __hip_atomic_load(&hb[1], __ATOMIC_RELAXED,
                                            __HIP_MEMORY_SCOPE_AGENT);
            unsigned v2 = __hip_atomic_load(&hb[2], __ATOMIC_RELAXED,
                                            __HIP_MEMORY_SCOPE_AGENT);
            unsigned v3 = __hip_atomic_load(&hb[3], __ATOMIC_RELAXED,
                                            __HIP_MEMORY_SCOPE_AGENT);
            float4 hv;
            hv.x = __uint_as_float(v0);
            hv.y = __uint_as_float(v1);
            hv.z = __uint_as_float(v2);
            hv.w = __uint_as_float(v3);
            ((float4*)h_lds)[tid] = hv;
        }
        __syncthreads();                                   // S2
    }

    if (wave == 0 && lane < 8) cfin[cu * 8 + lane] = c;
}

// ---------------------------------------------------------------------------
// Kernel C: preds = Hs @ Wy + by
// ---------------------------------------------------------------------------
__global__ __launch_bounds__(256) void y_gemm(
    const float* __restrict__ Hs, const float* __restrict__ Wy,
    const float* __restrict__ by, float* __restrict__ out)
{
    const int rb  = blockIdx.x * 16;
    const int tid = threadIdx.x;
    __shared__ float A[16][68];
    float acc[16];
#pragma unroll
    for (int r = 0; r < 16; ++r) acc[r] = 0.f;

    for (int k0 = 0; k0 < HID; k0 += 64) {
        __syncthreads();
        for (int i = tid; i < 16 * 64; i += 256) {
            int r = i >> 6, kk = i & 63;
            A[r][kk] = Hs[(size_t)(rb + r) * HID + k0 + kk];
        }
        __syncthreads();
#pragma unroll 8
        for (int kk = 0; kk < 64; ++kk) {
            float b = Wy[(size_t)(k0 + kk) * NCH + tid];
#pragma unroll
            for (int r = 0; r < 16; ++r) acc[r] += A[r][kk] * b;
        }
    }
    float bv = by[tid];
    for (int r = 0; r < 16; ++r)
        out[(size_t)(rb + r) * NCH + tid] = acc[r] + bv;
}

// ---------------------------------------------------------------------------
__global__ void fin_copy(const float* __restrict__ Hs,
                         const float* __restrict__ cfin,
                         float* __restrict__ out)
{
    int i = blockIdx.x * 256 + threadIdx.x;
    if (i < HID)
        out[(size_t)SEQL * NCH + i] = Hs[(size_t)(SEQL - 1) * HID + i];
    else
        out[(size_t)SEQL * NCH + i] = cfin[i - HID];
}

// ---------------------------------------------------------------------------
extern "C" void kernel_launch(void* const* d_in, const int* in_sizes, int n_in,
                              void* d_out, int out_size, void* d_ws, size_t ws_size,
                              hipStream_t stream)
{
    if (n_in < 14 || ws_size < WS_NEED) return;

    const int*   seq = (const int*)  d_in[0];
    const float* h0  = (const float*)d_in[1];
    const float* c0  = (const float*)d_in[2];
    const float* emb = (const float*)d_in[3];
    const float* Wf  = (const float*)d_in[4];
    const float* bf  = (const float*)d_in[5];
    const float* Wi  = (const float*)d_in[6];
    const float* bi  = (const float*)d_in[7];
    const float* Wo  = (const float*)d_in[8];
    const float* bo  = (const float*)d_in[9];
    const float* Wc  = (const float*)d_in[10];
    const float* bc  = (const float*)d_in[11];
    const float* Wy  = (const float*)d_in[12];
    const float* by  = (const float*)d_in[13];

    char* ws = (char*)d_ws;
    float*    Eg   = (float*)(ws + EG_OFF);
    float*    Hs   = (float*)(ws + HS_OFF);
    float*    hbuf = (float*)(ws + HB_OFF);
    float*    cfin = (float*)(ws + CF_OFF);
    unsigned* tags = (unsigned*)(ws + CT_OFF);
    float*    out  = (float*)d_out;

    hipMemsetAsync(tags, 0, CT_BYTES, stream);

    eg_gemm<<<256, 256, 0, stream>>>(emb, Wf, bf, Wi, bi, Wo, bo, Wc, bc, Eg);

    lstm_seq<<<256, 512, 0, stream>>>(seq, h0, c0, Wf, Wi, Wo, Wc, Eg,
                                      Hs, hbuf, cfin, tags);

    y_gemm<<<256, 256, 0, stream>>>(Hs, Wy, by, out);

    fin_copy<<<16, 256, 0, stream>>>(Hs, cfin, out);
}